// Round 11
// baseline (150.194 us; speedup 1.0000x reference)
//
#include <hip/hip_runtime.h>
#include <math.h>

#define BS 16
#define QN 900
#define NC 92
#define TN 100
#define NQ (BS * QN)        // 14400
#define NT (BS * TN)        // 1600
#define C_ELEMS ((size_t)NQ * NT)  // 23,040,000
#define NK 15               // scalar ownership (emit pass)
#define F4N 225             // float4 chunks per 900-col row
#define NS 16               // 4 float4-slots x 4 components per lane
#define ARR_CAP 300         // max ARR pops (tie-cycle guard)
#define UNM_CAP 416         // queue capacity: nunm(<=100) + kicks(<=ARR_CAP)
#define SLICE_F4 (TN * F4N) // 22500 float4s per batch slice (360 KB)

typedef float f32x4 __attribute__((ext_vector_type(4)));

// non-temporal float4 store: keeps the 92MB C-stream out of L2 so the
// solver's warmed cost_t slice isn't evicted (concurrent-kernel regime).
__device__ __forceinline__ void nt_store_f4(float4* p, float4 v) {
    f32x4 x; x.x = v.x; x.y = v.y; x.z = v.z; x.w = v.w;
    __builtin_nontemporal_store(x, (f32x4*)p);
}

// ---------------------------------------------------------------------------
// DPP full-wave f32 min: 6 dependent VALU ops, result valid in lane 63.
// ---------------------------------------------------------------------------
template<int CTRL>
__device__ __forceinline__ float dpp_fmin_step(float x) {
    int xi = __float_as_int(x);
    int yi = __builtin_amdgcn_update_dpp(xi, xi, CTRL, 0xF, 0xF, false);
    return fminf(x, __int_as_float(yi));
}
__device__ __forceinline__ float wave_fmin_to63(float x) {
    x = dpp_fmin_step<0x111>(x);  // row_shr:1
    x = dpp_fmin_step<0x112>(x);  // row_shr:2
    x = dpp_fmin_step<0x114>(x);  // row_shr:4
    x = dpp_fmin_step<0x118>(x);  // row_shr:8
    x = dpp_fmin_step<0x142>(x);  // row_bcast:15
    x = dpp_fmin_step<0x143>(x);  // row_bcast:31
    return x;
}
__device__ __forceinline__ float readlane63_f(float x) {
    return __uint_as_float(__builtin_amdgcn_readlane(__float_as_uint(x), 63));
}

// Fused (min, second-min) wave reduce; both valid in lane 63.
template<int CTRL>
__device__ __forceinline__ void dpp_fmin2_step(float& a1, float& a2) {
    int o1i = __builtin_amdgcn_update_dpp(__float_as_int(a1), __float_as_int(a1),
                                          CTRL, 0xF, 0xF, false);
    int o2i = __builtin_amdgcn_update_dpp(__float_as_int(a2), __float_as_int(a2),
                                          CTRL, 0xF, 0xF, false);
    float o1 = __int_as_float(o1i), o2 = __int_as_float(o2i);
    float hi = fmaxf(a1, o1);
    a1 = fminf(a1, o1);
    a2 = fminf(hi, fminf(a2, o2));
}
__device__ __forceinline__ void wave_fmin2_to63(float& a1, float& a2) {
    dpp_fmin2_step<0x111>(a1, a2);
    dpp_fmin2_step<0x112>(a1, a2);
    dpp_fmin2_step<0x114>(a1, a2);
    dpp_fmin2_step<0x118>(a1, a2);
    dpp_fmin2_step<0x142>(a1, a2);
    dpp_fmin2_step<0x143>(a1, a2);
}

// column c -> (slot, owner lane) under the float4 ownership map:
// c = 4*(lane + 64k) + j,  slot s = 4k + j
__device__ __forceinline__ int slot_of(int c) { return ((c >> 8) << 2) | (c & 3); }
__device__ __forceinline__ int owner_of(int c) { return (c >> 2) & 63; }

__device__ __forceinline__ int read_colreg16(const int arr[NS], int c) {
    int s = slot_of(c);
    int v = 0;
    #pragma unroll
    for (int k = 0; k < NS; ++k) if (k == s) v = arr[k];
    return __builtin_amdgcn_readlane(v, owner_of(c));
}

// uniform row-dual read from register mirrors (r is wave-uniform)
__device__ __forceinline__ float readrow_u(float u0, float u1, int r) {
    return __uint_as_float(__builtin_amdgcn_readlane(
        __float_as_uint(r < 64 ? u0 : u1), r & 63));
}

// issue one cost row (900 floats) as 4 dwordx4 loads per lane; irow is 1-based
__device__ __forceinline__ void issue_row(const float4* cst4, int irow, int lane,
        float4& r0, float4& r1, float4& r2, float4& r3) {
    const float4* cr = cst4 + (size_t)(irow - 1) * F4N;
    r0 = cr[lane];
    r1 = cr[lane + 64];
    r2 = cr[lane + 128];
    if (lane < 33) r3 = cr[lane + 192];
}

// ---------------------------------------------------------------------------
// cost of matching pred with target tb (xyxy).  (unchanged, passing since r1)
// ---------------------------------------------------------------------------
__device__ __forceinline__ float cost_entry(
        float px2, float py2, float pw, float ph,
        float ax0, float ay0, float ax1, float ay1,
        float area_a, float base_cls, float4 tb) {
    float tw = tb.z - tb.x;
    float th = tb.w - tb.y;
    float area_b = tw * th;
    float sx = px2 - (tb.x + tb.z);
    float sy = py2 - (tb.y + tb.w);
    float dw = pw - tw;
    float dh = ph - th;
    float cb = fmaf(0.5f, fabsf(sx), fabsf(dw)) + fmaf(0.5f, fabsf(sy), fabsf(dh));
    float ltx = fmaxf(ax0, tb.x), lty = fmaxf(ay0, tb.y);
    float rbx = fminf(ax1, tb.z), rby = fminf(ay1, tb.w);
    float iw = fmaxf(rbx - ltx, 0.0f), ih = fmaxf(rby - lty, 0.0f);
    float inter = iw * ih;
    float uni = (area_a + area_b) - inter;
    float cx0 = fminf(ax0, tb.x), cy0 = fminf(ay0, tb.y);
    float cx1 = fmaxf(ax1, tb.z), cy1 = fmaxf(ay1, tb.w);
    float area_c = (cx1 - cx0) * (cy1 - cy0);
    float num = fmaf(uni, uni, inter * area_c);
    float r   = __builtin_amdgcn_rcpf(uni * area_c);
    return fmaf(-2.0f, num * r, fmaf(5.0f, cb, base_cls));
}

// shared softmax helper: computes shp[wid][*] = 2 - p_cls for query q
__device__ __forceinline__ void softmax_to_lds(
        const float* __restrict__ logits, int q, int wid, int lane,
        float shp[4][NC]) {
    const float* row = logits + (size_t)q * NC;
    float x0 = (lane < NC) ? row[lane] : -INFINITY;
    float x1 = (lane + 64 < NC) ? row[lane + 64] : -INFINITY;
    float m = fmaxf(x0, x1);
    for (int off = 32; off; off >>= 1) m = fmaxf(m, __shfl_xor(m, off));
    float e0 = (lane < NC) ? expf(x0 - m) : 0.0f;
    float e1 = (lane + 64 < NC) ? expf(x1 - m) : 0.0f;
    float s = e0 + e1;
    for (int off = 32; off; off >>= 1) s += __shfl_xor(s, off);
    float rs = __builtin_amdgcn_rcpf(s);
    if (lane < NC) shp[wid][lane] = fmaf(-e0, rs, 2.0f);
    if (lane + 64 < NC) shp[wid][lane + 64] = fmaf(-e1, rs, 2.0f);
}

// ---------------------------------------------------------------------------
// Kernel A1: diagonal-block cost only -> cost_t.  (unchanged from round 10)
// ---------------------------------------------------------------------------
__global__ __launch_bounds__(256) void diag_cost_kernel(
        const float* __restrict__ logits,
        const float4* __restrict__ pboxes,
        const int4* __restrict__ tids4,
        const float4* __restrict__ tbox,
        float* __restrict__ cost_t) {
    __shared__ float shp[4][NC];
    int wid = threadIdx.x >> 6;
    int lane = threadIdx.x & 63;
    int q = blockIdx.x * 4 + wid;
    softmax_to_lds(logits, q, wid, lane, shp);
    __syncthreads();
    float4 pb = pboxes[q];
    float hx = pb.z * 0.5f, hy = pb.w * 0.5f;
    float ax0 = pb.x - hx, ay0 = pb.y - hy;
    float ax1 = pb.x + hx, ay1 = pb.y + hy;
    float area_a = pb.z * pb.w;
    float px2 = pb.x + pb.x, py2 = pb.y + pb.y;
    int b = q / QN;
    int diag_lo = b * 25;                 // diagonal chunk range [lo, lo+25)
    float* ctb = cost_t + (size_t)b * TN * QN + (q - b * QN);
    if (lane < 25) {
        int t4 = diag_lo + lane;
        int4 id = tids4[t4];
        int t = t4 * 4;
        float4 r;
        r.x = cost_entry(px2, py2, pb.z, pb.w, ax0, ay0, ax1, ay1, area_a,
                         shp[wid][id.x], tbox[t]);
        r.y = cost_entry(px2, py2, pb.z, pb.w, ax0, ay0, ax1, ay1, area_a,
                         shp[wid][id.y], tbox[t + 1]);
        r.z = cost_entry(px2, py2, pb.z, pb.w, ax0, ay0, ax1, ay1, area_a,
                         shp[wid][id.z], tbox[t + 2]);
        r.w = cost_entry(px2, py2, pb.z, pb.w, ax0, ay0, ax1, ay1, area_a,
                         shp[wid][id.w], tbox[t + 3]);
        float* dst = ctb + (size_t)(4 * lane) * QN;
        dst[0]        = r.x;
        dst[QN]       = r.y;
        dst[2 * QN]   = r.z;
        dst[3 * QN]   = r.w;
    }
}

// ---------------------------------------------------------------------------
// Kernel B2: parallel per-target rowmin+argmin.  (unchanged from round 10)
// ---------------------------------------------------------------------------
__global__ __launch_bounds__(256) void rowmin_kernel(
        const float* __restrict__ cost_t,
        unsigned long long* __restrict__ rm) {
    int wid = threadIdx.x >> 6;
    int lane = threadIdx.x & 63;
    int t = blockIdx.x * 4 + wid;          // global row in [0, NT)
    const float4* cr = (const float4*)(cost_t + (size_t)t * QN);
    float4 a0 = cr[lane];
    float4 a1 = cr[lane + 64];
    float4 a2 = cr[lane + 128];
    float4 a3 = make_float4(INFINITY, INFINITY, INFINITY, INFINITY);
    if (lane < 33) a3 = cr[lane + 192];
    float dd[NS];
    dd[0]  = a0.x; dd[1]  = a0.y; dd[2]  = a0.z; dd[3]  = a0.w;
    dd[4]  = a1.x; dd[5]  = a1.y; dd[6]  = a1.z; dd[7]  = a1.w;
    dd[8]  = a2.x; dd[9]  = a2.y; dd[10] = a2.z; dd[11] = a2.w;
    dd[12] = a3.x; dd[13] = a3.y; dd[14] = a3.z; dd[15] = a3.w;
    float l1 = INFINITY; int ls = 0;
    #pragma unroll
    for (int s = 0; s < NS; ++s) {
        bool lt = dd[s] < l1;
        ls = lt ? s : ls;
        l1 = lt ? dd[s] : l1;
    }
    float mv = readlane63_f(wave_fmin_to63(l1));
    unsigned long long eq = __ballot(l1 == mv);
    int wl = __ffsll(eq) - 1;
    int myq = (lane << 2) + ((ls >> 2) << 8) + (ls & 3);
    int ma = __builtin_amdgcn_readlane(myq, wl);
    if (lane == 0)
        rm[t] = ((unsigned long long)__float_as_uint(mv) << 32) | (unsigned)ma;
}

// ---------------------------------------------------------------------------
// Fused kernel: blocks 0..15 = Hungarian solver (byte-identical round-10
// body); blocks 16..3615 = full C-matrix computation.
// Round-11: C-writes use NON-TEMPORAL stores. C is write-once/never-read;
// the 92MB stream was evicting the solver's warmed cost_t slice from L2
// (~11.5MB/XCD of write traffic vs 4MB L2), re-exposing remote-latency on
// every ARR kick-row load. nt stores keep the stream out of L2.
// ---------------------------------------------------------------------------
__global__ __launch_bounds__(256, 1) void fused_cost_lsa_kernel(
        const float* __restrict__ logits,
        const float4* __restrict__ pboxes,
        const int4* __restrict__ tids4,
        const float4* __restrict__ tbox,
        const float* __restrict__ cost_t,
        const unsigned long long* __restrict__ rm,
        float* __restrict__ out) {
    __shared__ float shp[4][NC];
    __shared__ float u_s[TN];
    __shared__ int p_s[QN];
    __shared__ int unm[UNM_CAP];
    __shared__ int dij[UNM_CAP];

    if (blockIdx.x >= 16) {
        // ---------------- cost path: full C matrix ------------------------
        int wid = threadIdx.x >> 6;
        int lane = threadIdx.x & 63;
        int q = (blockIdx.x - 16) * 4 + wid;
        softmax_to_lds(logits, q, wid, lane, shp);
        __syncthreads();
        float4 pb = pboxes[q];
        float hx = pb.z * 0.5f, hy = pb.w * 0.5f;
        float ax0 = pb.x - hx, ay0 = pb.y - hy;
        float ax1 = pb.x + hx, ay1 = pb.y + hy;
        float area_a = pb.z * pb.w;
        float px2 = pb.x + pb.x, py2 = pb.y + pb.y;
        float4* crow4 = (float4*)(out + (size_t)q * NT);
        #pragma unroll 2
        for (int t4 = lane; t4 < NT / 4; t4 += 64) {
            int4 id = tids4[t4];
            int t = t4 * 4;
            float4 r;
            r.x = cost_entry(px2, py2, pb.z, pb.w, ax0, ay0, ax1, ay1, area_a,
                             shp[wid][id.x], tbox[t]);
            r.y = cost_entry(px2, py2, pb.z, pb.w, ax0, ay0, ax1, ay1, area_a,
                             shp[wid][id.y], tbox[t + 1]);
            r.z = cost_entry(px2, py2, pb.z, pb.w, ax0, ay0, ax1, ay1, area_a,
                             shp[wid][id.z], tbox[t + 2]);
            r.w = cost_entry(px2, py2, pb.z, pb.w, ax0, ay0, ax1, ay1, area_a,
                             shp[wid][id.w], tbox[t + 3]);
            nt_store_f4(&crow4[t4], r);   // non-temporal: don't pollute L2
        }
        return;
    }

    // ---------------- solver path (round-10 body, byte-identical) ---------
    int b = blockIdx.x;
    int wv = threadIdx.x >> 6;
    int lane = threadIdx.x & 63;
    const float4* cst4 = (const float4*)(cost_t + (size_t)b * TN * QN);

    if (wv != 0) {
        // warming waves: pull batch slice into local XCD L2, then exit
        int start = (wv - 1) * (SLICE_F4 / 3);
        int end   = (wv == 3) ? SLICE_F4 : wv * (SLICE_F4 / 3);
        float acc = 0.0f;
        #pragma unroll 4
        for (int i = start + lane; i < end; i += 64) {
            float4 x = cst4[i];
            acc += (x.x + x.y) + (x.z + x.w);
        }
        asm volatile("" :: "v"(acc));   // keep loads live (DCE guard)
        return;
    }

    float v_r[NS], dist_r[NS];
    int way_r[NS], pcol_r[NS];
    float4 pre0, pre1, pre2, pre3 = make_float4(0.f, 0.f, 0.f, 0.f);
    float4 rc0, rc1, rc2, rc3 = make_float4(0.f, 0.f, 0.f, 0.f);
    const bool v3 = (lane < 33);   // slot 12-15 validity: lane+192 < 225

    #pragma unroll
    for (int s = 0; s < NS; ++s) v_r[s] = 0.0f;
    for (int j = lane; j < QN; j += 64) p_s[j] = 0x7fffffff;

    // --- init: decode rowmin u64, set duals -------------------------------
    int arg0 = 0, arg1 = 0;
    float u0 = 0.0f, u1 = 0.0f;
    {
        unsigned long long k0 = rm[b * TN + lane];
        u0 = __uint_as_float((unsigned)(k0 >> 32));
        arg0 = (int)(k0 & 0xffffffffu);
        u_s[lane] = u0;
        if (lane + 64 < TN) {
            unsigned long long k1 = rm[b * TN + lane + 64];
            u1 = __uint_as_float((unsigned)(k1 >> 32));
            arg1 = (int)(k1 & 0xffffffffu);
            u_s[lane + 64] = u1;
        }
    }

    // --- greedy: column argmin taken by smallest row index ----------------
    atomicMin(&p_s[arg0], lane + 1);
    if (lane + 64 < TN) atomicMin(&p_s[arg1], lane + 65);
    int nunm = 0;
    {
        bool um0 = (p_s[arg0] != lane + 1);
        unsigned long long m0 = __ballot(um0);
        if (um0) unm[__popcll(m0 & ((1ull << lane) - 1ull))] = lane + 1;
        nunm = __popcll(m0);
        bool um1 = (lane + 64 < TN) && (p_s[arg1] != lane + 65);
        unsigned long long m1 = __ballot(um1);
        if (um1) unm[nunm + __popcll(m1 & ((1ull << lane) - 1ull))] = lane + 65;
        nunm += __popcll(m1);
    }
    #pragma unroll
    for (int s = 0; s < NS; ++s) {
        int f = lane + ((s >> 2) << 6);
        int c = (f << 2) | (s & 3);
        pcol_r[s] = 0;
        if (f < F4N) { int pv = p_s[c]; pcol_r[s] = (pv == 0x7fffffff) ? 0 : pv; }
    }

    // --- ARR phase: resolve greedy collisions cheaply ---------------------
    int qhead = 0, qtail = nunm, dij_n = 0, pops = 0;
    if (qhead < qtail) issue_row(cst4, unm[0], lane, pre0, pre1, pre2, pre3);
    while (qhead < qtail) {
        int i_cur = unm[qhead++];
        ++pops;
        if (pops > ARR_CAP) {           // tie-cycle guard: drain rest to Dijkstra
            if (lane == 0) dij[dij_n] = i_cur;
            dij_n++;
            continue;                   // pre never consumed after cap
        }
        // d = row - v  (pre holds row i_cur)
        float dd[NS];
        dd[0]  = pre0.x - v_r[0];  dd[1]  = pre0.y - v_r[1];
        dd[2]  = pre0.z - v_r[2];  dd[3]  = pre0.w - v_r[3];
        dd[4]  = pre1.x - v_r[4];  dd[5]  = pre1.y - v_r[5];
        dd[6]  = pre1.z - v_r[6];  dd[7]  = pre1.w - v_r[7];
        dd[8]  = pre2.x - v_r[8];  dd[9]  = pre2.y - v_r[9];
        dd[10] = pre2.z - v_r[10]; dd[11] = pre2.w - v_r[11];
        if (v3) {
            dd[12] = pre3.x - v_r[12]; dd[13] = pre3.y - v_r[13];
            dd[14] = pre3.z - v_r[14]; dd[15] = pre3.w - v_r[15];
        } else {
            dd[12] = INFINITY; dd[13] = INFINITY;
            dd[14] = INFINITY; dd[15] = INFINITY;
        }
        // prefetch next queued row (latency hides under the reduce below)
        bool pf = false;
        if (qhead < qtail) { issue_row(cst4, unm[qhead], lane, pre0, pre1, pre2, pre3); pf = true; }
        // local depth-4 pairwise tree: (val, sec, slot, pcol); left wins ties
        float a1[NS], a2[NS]; int ai[NS], ap[NS];
        #pragma unroll
        for (int s = 0; s < NS; ++s) {
            a1[s] = dd[s]; a2[s] = INFINITY; ai[s] = s; ap[s] = pcol_r[s];
        }
        #pragma unroll
        for (int n = 8; n >= 1; n >>= 1) {
            #pragma unroll
            for (int i = 0; i < n; ++i) {
                bool tk = a1[2 * i + 1] < a1[2 * i];
                float m1 = tk ? a1[2 * i + 1] : a1[2 * i];
                float ms = tk ? fminf(a1[2 * i], a2[2 * i + 1])
                              : fminf(a1[2 * i + 1], a2[2 * i]);
                a1[i] = m1; a2[i] = ms;
                ai[i] = tk ? ai[2 * i + 1] : ai[2 * i];
                ap[i] = tk ? ap[2 * i + 1] : ap[2 * i];
            }
        }
        float lmin = a1[0];
        int ls = ai[0];
        int pv = ap[0];
        int myj = (lane << 2) + ((ls >> 2) << 8) + (ls & 3);
        float w1 = a1[0], w2 = a2[0];
        wave_fmin2_to63(w1, w2);
        float d1 = readlane63_f(w1);
        float d2 = readlane63_f(w2);
        unsigned long long eqm = __ballot(lmin == d1);
        int wl = __ffsll(eqm) - 1;
        int j1 = __builtin_amdgcn_readlane(myj, wl);
        int i0 = __builtin_amdgcn_readlane(pv, wl);
        bool take = (d1 < d2) || (i0 == 0);
        if (take) {
            if (i0 != 0) {
                // kicked row is the next pop when queue was empty: issue NOW
                if (!pf) issue_row(cst4, i0, lane, pre0, pre1, pre2, pre3);
                if (lane == 0) unm[qtail] = i0;
                qtail++;
            }
            int s1 = slot_of(j1), ow = owner_of(j1);
            float dv_ = d2 - d1;
            #pragma unroll
            for (int s = 0; s < NS; ++s)
                if (s == s1 && lane == ow) { v_r[s] -= dv_; pcol_r[s] = i_cur; }
            if (lane == 0) u_s[i_cur - 1] = d2;
        } else {
            if (lane == 0) { u_s[i_cur - 1] = d2; dij[dij_n] = i_cur; }
            dij_n++;
        }
    }
    // refresh register u mirrors after ARR writes
    u0 = u_s[lane];
    if (lane + 64 < TN) u1 = u_s[lane + 64];

    // --- shortest augmenting path for rows ARR couldn't place -------------
    if (dij_n > 0) issue_row(cst4, dij[0], lane, pre0, pre1, pre2, pre3);

    for (int ui = 0; ui < dij_n; ++ui) {
        int i_cur = dij[ui];
        unsigned used_mask = 0;
        float uic = readrow_u(u0, u1, i_cur - 1);
        #pragma unroll
        for (int s = 0; s < NS; ++s) way_r[s] = -1;
        dist_r[0]  = (pre0.x - uic) - v_r[0];
        dist_r[1]  = (pre0.y - uic) - v_r[1];
        dist_r[2]  = (pre0.z - uic) - v_r[2];
        dist_r[3]  = (pre0.w - uic) - v_r[3];
        dist_r[4]  = (pre1.x - uic) - v_r[4];
        dist_r[5]  = (pre1.y - uic) - v_r[5];
        dist_r[6]  = (pre1.z - uic) - v_r[6];
        dist_r[7]  = (pre1.w - uic) - v_r[7];
        dist_r[8]  = (pre2.x - uic) - v_r[8];
        dist_r[9]  = (pre2.y - uic) - v_r[9];
        dist_r[10] = (pre2.z - uic) - v_r[10];
        dist_r[11] = (pre2.w - uic) - v_r[11];
        if (v3) {
            dist_r[12] = (pre3.x - uic) - v_r[12];
            dist_r[13] = (pre3.y - uic) - v_r[13];
            dist_r[14] = (pre3.z - uic) - v_r[14];
            dist_r[15] = (pre3.w - uic) - v_r[15];
        } else {
            dist_r[12] = INFINITY; dist_r[13] = INFINITY;
            dist_r[14] = INFINITY; dist_r[15] = INFINITY;
        }
        if (ui + 1 < dij_n) issue_row(cst4, dij[ui + 1], lane, pre0, pre1, pre2, pre3);

        float dfin; int jfree;
        while (true) {
            // depth-4 pairwise min-tree with (slot, pcol) payload
            float dv[NS]; int dk[NS]; int pc[NS];
            #pragma unroll
            for (int s = 0; s < NS; ++s) {
                dv[s] = (used_mask & (1u << s)) ? INFINITY : dist_r[s];
                dk[s] = s;
                pc[s] = pcol_r[s];
            }
            #pragma unroll
            for (int n = 8; n >= 1; n >>= 1) {
                #pragma unroll
                for (int i = 0; i < n; ++i) {
                    bool tk = dv[2 * i + 1] < dv[2 * i];
                    dv[i] = tk ? dv[2 * i + 1] : dv[2 * i];
                    dk[i] = tk ? dk[2 * i + 1] : dk[2 * i];
                    pc[i] = tk ? pc[2 * i + 1] : pc[2 * i];
                }
            }
            float lv = dv[0];
            int s0 = dk[0];
            int li = (lane << 2) + ((s0 >> 2) << 8) + (s0 & 3);
            float dmin = readlane63_f(wave_fmin_to63(lv));
            unsigned long long eq = __ballot(lv == dmin);
            int winner = __ffsll(eq) - 1;
            int j1 = __builtin_amdgcn_readlane(li, winner);
            int pj1 = __builtin_amdgcn_readlane(pc[0], winner);
            if (pj1 == 0) { dfin = dmin; jfree = j1; break; }
            {
                int s1 = slot_of(j1), ow1 = owner_of(j1);
                if (lane == ow1) used_mask |= (1u << s1);
            }
            // row pj1 load issued first; readlane/bookkeeping overlap latency
            issue_row(cst4, pj1, lane, rc0, rc1, rc2, rc3);
            float ui0 = readrow_u(u0, u1, pj1 - 1);
            float off = dmin - ui0;   // wave-uniform
            #define RELAX(S, V) \
                if (!(used_mask & (1u << (S)))) { \
                    float nd = ((V) - v_r[S]) + off; \
                    if (nd < dist_r[S]) { dist_r[S] = nd; way_r[S] = j1; } }
            RELAX(0,  rc0.x) RELAX(1,  rc0.y) RELAX(2,  rc0.z) RELAX(3,  rc0.w)
            RELAX(4,  rc1.x) RELAX(5,  rc1.y) RELAX(6,  rc1.z) RELAX(7,  rc1.w)
            RELAX(8,  rc2.x) RELAX(9,  rc2.y) RELAX(10, rc2.z) RELAX(11, rc2.w)
            if (v3) {
                RELAX(12, rc3.x) RELAX(13, rc3.y) RELAX(14, rc3.z) RELAX(15, rc3.w)
            }
            #undef RELAX
        }
        // dual updates (once per path); pcol_r unchanged until augment below
        #pragma unroll
        for (int s = 0; s < NS; ++s) {
            if (used_mask & (1u << s)) {
                float a = dfin - dist_r[s];
                v_r[s] -= a;
                u_s[pcol_r[s] - 1] += a;   // distinct rows => distinct addresses
            }
        }
        if (lane == 0) u_s[i_cur - 1] += dfin;
        u0 = u_s[lane];
        if (lane + 64 < TN) u1 = u_s[lane + 64];
        // augment: walk way chain from the free column
        {
            int jj = jfree;
            while (true) {
                int wj = read_colreg16(way_r, jj);
                int pn = (wj < 0) ? i_cur : read_colreg16(pcol_r, wj);
                int sj = slot_of(jj), ow = owner_of(jj);
                #pragma unroll
                for (int s = 0; s < NS; ++s)
                    if (s == sj && lane == ow) pcol_r[s] = pn;
                if (wj < 0) break;
                jj = wj;
            }
        }
    }

    // --- emit: write pcol back to LDS by column for ascending-order pass --
    #pragma unroll
    for (int s = 0; s < NS; ++s) {
        int f = lane + ((s >> 2) << 6);
        int c = (f << 2) | (s & 3);
        if (f < F4N) p_s[c] = pcol_r[s];
    }
    float* rows = out + C_ELEMS + (size_t)b * TN;
    float* cols = out + C_ELEMS + (size_t)BS * TN + (size_t)b * TN;
    int base = 0;
    #pragma unroll
    for (int k = 0; k < NK; ++k) {
        int c = lane + (k << 6);
        int pv = (c < QN) ? p_s[c] : 0;
        unsigned long long mask = __ballot(pv > 0);
        if (pv > 0) {
            int rank = base + __popcll(mask & ((1ull << lane) - 1ull));
            rows[rank] = (float)c;
            cols[rank] = (float)(pv - 1);
        }
        base += __popcll(mask);
    }
}

extern "C" void kernel_launch(void* const* d_in, const int* in_sizes, int n_in,
                              void* d_out, int out_size, void* d_ws, size_t ws_size,
                              hipStream_t stream) {
    const float* logits = (const float*)d_in[0];        // (16,900,92)
    const float4* pboxes = (const float4*)d_in[1];      // (16,900,4) cxcywh
    const int* tids = (const int*)d_in[2];              // (1600,)
    const float4* tbox = (const float4*)d_in[3];        // (1600,4) xyxy
    float* out = (float*)d_out;

    float* cost_t = (float*)d_ws;                       // BS*TN*QN floats (5.76 MB)
    unsigned long long* rm =
        (unsigned long long*)(cost_t + (size_t)BS * TN * QN);  // NT u64 (8B-aligned)

    diag_cost_kernel<<<NQ / 4, 256, 0, stream>>>(logits, pboxes, (const int4*)tids, tbox, cost_t);
    rowmin_kernel<<<NT / 4, 256, 0, stream>>>(cost_t, rm);
    fused_cost_lsa_kernel<<<16 + NQ / 4, 256, 0, stream>>>(
        logits, pboxes, (const int4*)tids, tbox, cost_t, rm, out);
}

// Round 12
// 145.172 us; speedup vs baseline: 1.0346x; 1.0346x over previous
//
#include <hip/hip_runtime.h>
#include <math.h>

#define BS 16
#define QN 900
#define NC 92
#define TN 100
#define NQ (BS * QN)        // 14400
#define NT (BS * TN)        // 1600
#define C_ELEMS ((size_t)NQ * NT)  // 23,040,000
#define NK 15               // scalar ownership (emit pass)
#define F4N 225             // float4 chunks per 900-col row
#define NS 16               // 4 float4-slots x 4 components per lane
#define ARR_CAP 300         // max ARR pops (tie-cycle guard)
#define UNM_CAP 416         // queue capacity: nunm(<=100) + kicks(<=ARR_CAP)
#define SLICE_F4 (TN * F4N) // 22500 float4s per batch slice (360 KB)

// ---------------------------------------------------------------------------
// DPP full-wave f32 min: 6 dependent VALU ops, result valid in lane 63.
// ---------------------------------------------------------------------------
template<int CTRL>
__device__ __forceinline__ float dpp_fmin_step(float x) {
    int xi = __float_as_int(x);
    int yi = __builtin_amdgcn_update_dpp(xi, xi, CTRL, 0xF, 0xF, false);
    return fminf(x, __int_as_float(yi));
}
__device__ __forceinline__ float wave_fmin_to63(float x) {
    x = dpp_fmin_step<0x111>(x);  // row_shr:1
    x = dpp_fmin_step<0x112>(x);  // row_shr:2
    x = dpp_fmin_step<0x114>(x);  // row_shr:4
    x = dpp_fmin_step<0x118>(x);  // row_shr:8
    x = dpp_fmin_step<0x142>(x);  // row_bcast:15
    x = dpp_fmin_step<0x143>(x);  // row_bcast:31
    return x;
}
__device__ __forceinline__ float readlane63_f(float x) {
    return __uint_as_float(__builtin_amdgcn_readlane(__float_as_uint(x), 63));
}

// Fused (min, second-min) wave reduce; both valid in lane 63.
template<int CTRL>
__device__ __forceinline__ void dpp_fmin2_step(float& a1, float& a2) {
    int o1i = __builtin_amdgcn_update_dpp(__float_as_int(a1), __float_as_int(a1),
                                          CTRL, 0xF, 0xF, false);
    int o2i = __builtin_amdgcn_update_dpp(__float_as_int(a2), __float_as_int(a2),
                                          CTRL, 0xF, 0xF, false);
    float o1 = __int_as_float(o1i), o2 = __int_as_float(o2i);
    float hi = fmaxf(a1, o1);
    a1 = fminf(a1, o1);
    a2 = fminf(hi, fminf(a2, o2));
}
__device__ __forceinline__ void wave_fmin2_to63(float& a1, float& a2) {
    dpp_fmin2_step<0x111>(a1, a2);
    dpp_fmin2_step<0x112>(a1, a2);
    dpp_fmin2_step<0x114>(a1, a2);
    dpp_fmin2_step<0x118>(a1, a2);
    dpp_fmin2_step<0x142>(a1, a2);
    dpp_fmin2_step<0x143>(a1, a2);
}

// column c -> (slot, owner lane) under the float4 ownership map:
// c = 4*(lane + 64k) + j,  slot s = 4k + j
__device__ __forceinline__ int slot_of(int c) { return ((c >> 8) << 2) | (c & 3); }
__device__ __forceinline__ int owner_of(int c) { return (c >> 2) & 63; }

__device__ __forceinline__ int read_colreg16(const int arr[NS], int c) {
    int s = slot_of(c);
    int v = 0;
    #pragma unroll
    for (int k = 0; k < NS; ++k) if (k == s) v = arr[k];
    return __builtin_amdgcn_readlane(v, owner_of(c));
}

// uniform row-dual read from register mirrors (r is wave-uniform)
__device__ __forceinline__ float readrow_u(float u0, float u1, int r) {
    return __uint_as_float(__builtin_amdgcn_readlane(
        __float_as_uint(r < 64 ? u0 : u1), r & 63));
}

// issue one cost row (900 floats) as 4 dwordx4 loads per lane; irow is 1-based
__device__ __forceinline__ void issue_row(const float4* cst4, int irow, int lane,
        float4& r0, float4& r1, float4& r2, float4& r3) {
    const float4* cr = cst4 + (size_t)(irow - 1) * F4N;
    r0 = cr[lane];
    r1 = cr[lane + 64];
    r2 = cr[lane + 128];
    if (lane < 33) r3 = cr[lane + 192];
}

// ---------------------------------------------------------------------------
// cost of matching pred with target tb (xyxy).  (unchanged, passing since r1)
// ---------------------------------------------------------------------------
__device__ __forceinline__ float cost_entry(
        float px2, float py2, float pw, float ph,
        float ax0, float ay0, float ax1, float ay1,
        float area_a, float base_cls, float4 tb) {
    float tw = tb.z - tb.x;
    float th = tb.w - tb.y;
    float area_b = tw * th;
    float sx = px2 - (tb.x + tb.z);
    float sy = py2 - (tb.y + tb.w);
    float dw = pw - tw;
    float dh = ph - th;
    float cb = fmaf(0.5f, fabsf(sx), fabsf(dw)) + fmaf(0.5f, fabsf(sy), fabsf(dh));
    float ltx = fmaxf(ax0, tb.x), lty = fmaxf(ay0, tb.y);
    float rbx = fminf(ax1, tb.z), rby = fminf(ay1, tb.w);
    float iw = fmaxf(rbx - ltx, 0.0f), ih = fmaxf(rby - lty, 0.0f);
    float inter = iw * ih;
    float uni = (area_a + area_b) - inter;
    float cx0 = fminf(ax0, tb.x), cy0 = fminf(ay0, tb.y);
    float cx1 = fmaxf(ax1, tb.z), cy1 = fmaxf(ay1, tb.w);
    float area_c = (cx1 - cx0) * (cy1 - cy0);
    float num = fmaf(uni, uni, inter * area_c);
    float r   = __builtin_amdgcn_rcpf(uni * area_c);
    return fmaf(-2.0f, num * r, fmaf(5.0f, cb, base_cls));
}

// shared softmax helper: computes shp[wid][*] = 2 - p_cls for query q
__device__ __forceinline__ void softmax_to_lds(
        const float* __restrict__ logits, int q, int wid, int lane,
        float shp[4][NC]) {
    const float* row = logits + (size_t)q * NC;
    float x0 = (lane < NC) ? row[lane] : -INFINITY;
    float x1 = (lane + 64 < NC) ? row[lane + 64] : -INFINITY;
    float m = fmaxf(x0, x1);
    for (int off = 32; off; off >>= 1) m = fmaxf(m, __shfl_xor(m, off));
    float e0 = (lane < NC) ? expf(x0 - m) : 0.0f;
    float e1 = (lane + 64 < NC) ? expf(x1 - m) : 0.0f;
    float s = e0 + e1;
    for (int off = 32; off; off >>= 1) s += __shfl_xor(s, off);
    float rs = __builtin_amdgcn_rcpf(s);
    if (lane < NC) shp[wid][lane] = fmaf(-e0, rs, 2.0f);
    if (lane + 64 < NC) shp[wid][lane + 64] = fmaf(-e1, rs, 2.0f);
}

// ---------------------------------------------------------------------------
// Kernel A1: diagonal-block cost only -> cost_t.  (unchanged from round 10)
// ---------------------------------------------------------------------------
__global__ __launch_bounds__(256) void diag_cost_kernel(
        const float* __restrict__ logits,
        const float4* __restrict__ pboxes,
        const int4* __restrict__ tids4,
        const float4* __restrict__ tbox,
        float* __restrict__ cost_t) {
    __shared__ float shp[4][NC];
    int wid = threadIdx.x >> 6;
    int lane = threadIdx.x & 63;
    int q = blockIdx.x * 4 + wid;
    softmax_to_lds(logits, q, wid, lane, shp);
    __syncthreads();
    float4 pb = pboxes[q];
    float hx = pb.z * 0.5f, hy = pb.w * 0.5f;
    float ax0 = pb.x - hx, ay0 = pb.y - hy;
    float ax1 = pb.x + hx, ay1 = pb.y + hy;
    float area_a = pb.z * pb.w;
    float px2 = pb.x + pb.x, py2 = pb.y + pb.y;
    int b = q / QN;
    int diag_lo = b * 25;                 // diagonal chunk range [lo, lo+25)
    float* ctb = cost_t + (size_t)b * TN * QN + (q - b * QN);
    if (lane < 25) {
        int t4 = diag_lo + lane;
        int4 id = tids4[t4];
        int t = t4 * 4;
        float4 r;
        r.x = cost_entry(px2, py2, pb.z, pb.w, ax0, ay0, ax1, ay1, area_a,
                         shp[wid][id.x], tbox[t]);
        r.y = cost_entry(px2, py2, pb.z, pb.w, ax0, ay0, ax1, ay1, area_a,
                         shp[wid][id.y], tbox[t + 1]);
        r.z = cost_entry(px2, py2, pb.z, pb.w, ax0, ay0, ax1, ay1, area_a,
                         shp[wid][id.z], tbox[t + 2]);
        r.w = cost_entry(px2, py2, pb.z, pb.w, ax0, ay0, ax1, ay1, area_a,
                         shp[wid][id.w], tbox[t + 3]);
        float* dst = ctb + (size_t)(4 * lane) * QN;
        dst[0]        = r.x;
        dst[QN]       = r.y;
        dst[2 * QN]   = r.z;
        dst[3 * QN]   = r.w;
    }
}

// ---------------------------------------------------------------------------
// Kernel B2: parallel per-target rowmin+argmin.  (unchanged from round 10)
// ---------------------------------------------------------------------------
__global__ __launch_bounds__(256) void rowmin_kernel(
        const float* __restrict__ cost_t,
        unsigned long long* __restrict__ rm) {
    int wid = threadIdx.x >> 6;
    int lane = threadIdx.x & 63;
    int t = blockIdx.x * 4 + wid;          // global row in [0, NT)
    const float4* cr = (const float4*)(cost_t + (size_t)t * QN);
    float4 a0 = cr[lane];
    float4 a1 = cr[lane + 64];
    float4 a2 = cr[lane + 128];
    float4 a3 = make_float4(INFINITY, INFINITY, INFINITY, INFINITY);
    if (lane < 33) a3 = cr[lane + 192];
    float dd[NS];
    dd[0]  = a0.x; dd[1]  = a0.y; dd[2]  = a0.z; dd[3]  = a0.w;
    dd[4]  = a1.x; dd[5]  = a1.y; dd[6]  = a1.z; dd[7]  = a1.w;
    dd[8]  = a2.x; dd[9]  = a2.y; dd[10] = a2.z; dd[11] = a2.w;
    dd[12] = a3.x; dd[13] = a3.y; dd[14] = a3.z; dd[15] = a3.w;
    float l1 = INFINITY; int ls = 0;
    #pragma unroll
    for (int s = 0; s < NS; ++s) {
        bool lt = dd[s] < l1;
        ls = lt ? s : ls;
        l1 = lt ? dd[s] : l1;
    }
    float mv = readlane63_f(wave_fmin_to63(l1));
    unsigned long long eq = __ballot(l1 == mv);
    int wl = __ffsll(eq) - 1;
    int myq = (lane << 2) + ((ls >> 2) << 8) + (ls & 3);
    int ma = __builtin_amdgcn_readlane(myq, wl);
    if (lane == 0)
        rm[t] = ((unsigned long long)__float_as_uint(mv) << 32) | (unsigned)ma;
}

// ---------------------------------------------------------------------------
// Fused kernel: blocks 0..15 = Hungarian solver; blocks 16..3615 = full
// C-matrix computation.
// Round-12: (a) REVERTED round-11's non-temporal C stores (regressed +4.6us:
// lost L2 write-coalescing cost more than the solver gained -- thrash theory
// wrong). (b) Solver wave runs at s_setprio(3): its CU hosts ~7 cost blocks
// (~28 throughput waves) that dilute the serial dependent chain's issue
// slots; priority gives the latency-critical wave first claim on issue while
// cost waves still fill its (many) stall cycles. Cost/warming waves stay 0.
// ---------------------------------------------------------------------------
__global__ __launch_bounds__(256, 1) void fused_cost_lsa_kernel(
        const float* __restrict__ logits,
        const float4* __restrict__ pboxes,
        const int4* __restrict__ tids4,
        const float4* __restrict__ tbox,
        const float* __restrict__ cost_t,
        const unsigned long long* __restrict__ rm,
        float* __restrict__ out) {
    __shared__ float shp[4][NC];
    __shared__ float u_s[TN];
    __shared__ int p_s[QN];
    __shared__ int unm[UNM_CAP];
    __shared__ int dij[UNM_CAP];

    if (blockIdx.x >= 16) {
        // ---------------- cost path: full C matrix ------------------------
        int wid = threadIdx.x >> 6;
        int lane = threadIdx.x & 63;
        int q = (blockIdx.x - 16) * 4 + wid;
        softmax_to_lds(logits, q, wid, lane, shp);
        __syncthreads();
        float4 pb = pboxes[q];
        float hx = pb.z * 0.5f, hy = pb.w * 0.5f;
        float ax0 = pb.x - hx, ay0 = pb.y - hy;
        float ax1 = pb.x + hx, ay1 = pb.y + hy;
        float area_a = pb.z * pb.w;
        float px2 = pb.x + pb.x, py2 = pb.y + pb.y;
        float4* crow4 = (float4*)(out + (size_t)q * NT);
        #pragma unroll 2
        for (int t4 = lane; t4 < NT / 4; t4 += 64) {
            int4 id = tids4[t4];
            int t = t4 * 4;
            float4 r;
            r.x = cost_entry(px2, py2, pb.z, pb.w, ax0, ay0, ax1, ay1, area_a,
                             shp[wid][id.x], tbox[t]);
            r.y = cost_entry(px2, py2, pb.z, pb.w, ax0, ay0, ax1, ay1, area_a,
                             shp[wid][id.y], tbox[t + 1]);
            r.z = cost_entry(px2, py2, pb.z, pb.w, ax0, ay0, ax1, ay1, area_a,
                             shp[wid][id.z], tbox[t + 2]);
            r.w = cost_entry(px2, py2, pb.z, pb.w, ax0, ay0, ax1, ay1, area_a,
                             shp[wid][id.w], tbox[t + 3]);
            crow4[t4] = r;   // plain store (round-11 nt-store reverted)
        }
        return;
    }

    // ---------------- solver path ----------------------------------------
    int b = blockIdx.x;
    int wv = threadIdx.x >> 6;
    int lane = threadIdx.x & 63;
    const float4* cst4 = (const float4*)(cost_t + (size_t)b * TN * QN);

    if (wv != 0) {
        // warming waves: pull batch slice into local XCD L2, then exit
        int start = (wv - 1) * (SLICE_F4 / 3);
        int end   = (wv == 3) ? SLICE_F4 : wv * (SLICE_F4 / 3);
        float acc = 0.0f;
        #pragma unroll 4
        for (int i = start + lane; i < end; i += 64) {
            float4 x = cst4[i];
            acc += (x.x + x.y) + (x.z + x.w);
        }
        asm volatile("" :: "v"(acc));   // keep loads live (DCE guard)
        return;
    }

    // latency-critical serial wave: claim issue priority over co-resident
    // throughput waves (they fill our stall cycles; we never wait on them).
    __builtin_amdgcn_s_setprio(3);

    float v_r[NS], dist_r[NS];
    int way_r[NS], pcol_r[NS];
    float4 pre0, pre1, pre2, pre3 = make_float4(0.f, 0.f, 0.f, 0.f);
    float4 rc0, rc1, rc2, rc3 = make_float4(0.f, 0.f, 0.f, 0.f);
    const bool v3 = (lane < 33);   // slot 12-15 validity: lane+192 < 225

    #pragma unroll
    for (int s = 0; s < NS; ++s) v_r[s] = 0.0f;
    for (int j = lane; j < QN; j += 64) p_s[j] = 0x7fffffff;

    // --- init: decode rowmin u64, set duals -------------------------------
    int arg0 = 0, arg1 = 0;
    float u0 = 0.0f, u1 = 0.0f;
    {
        unsigned long long k0 = rm[b * TN + lane];
        u0 = __uint_as_float((unsigned)(k0 >> 32));
        arg0 = (int)(k0 & 0xffffffffu);
        u_s[lane] = u0;
        if (lane + 64 < TN) {
            unsigned long long k1 = rm[b * TN + lane + 64];
            u1 = __uint_as_float((unsigned)(k1 >> 32));
            arg1 = (int)(k1 & 0xffffffffu);
            u_s[lane + 64] = u1;
        }
    }

    // --- greedy: column argmin taken by smallest row index ----------------
    atomicMin(&p_s[arg0], lane + 1);
    if (lane + 64 < TN) atomicMin(&p_s[arg1], lane + 65);
    int nunm = 0;
    {
        bool um0 = (p_s[arg0] != lane + 1);
        unsigned long long m0 = __ballot(um0);
        if (um0) unm[__popcll(m0 & ((1ull << lane) - 1ull))] = lane + 1;
        nunm = __popcll(m0);
        bool um1 = (lane + 64 < TN) && (p_s[arg1] != lane + 65);
        unsigned long long m1 = __ballot(um1);
        if (um1) unm[nunm + __popcll(m1 & ((1ull << lane) - 1ull))] = lane + 65;
        nunm += __popcll(m1);
    }
    #pragma unroll
    for (int s = 0; s < NS; ++s) {
        int f = lane + ((s >> 2) << 6);
        int c = (f << 2) | (s & 3);
        pcol_r[s] = 0;
        if (f < F4N) { int pv = p_s[c]; pcol_r[s] = (pv == 0x7fffffff) ? 0 : pv; }
    }

    // --- ARR phase: resolve greedy collisions cheaply ---------------------
    int qhead = 0, qtail = nunm, dij_n = 0, pops = 0;
    if (qhead < qtail) issue_row(cst4, unm[0], lane, pre0, pre1, pre2, pre3);
    while (qhead < qtail) {
        int i_cur = unm[qhead++];
        ++pops;
        if (pops > ARR_CAP) {           // tie-cycle guard: drain rest to Dijkstra
            if (lane == 0) dij[dij_n] = i_cur;
            dij_n++;
            continue;                   // pre never consumed after cap
        }
        // d = row - v  (pre holds row i_cur)
        float dd[NS];
        dd[0]  = pre0.x - v_r[0];  dd[1]  = pre0.y - v_r[1];
        dd[2]  = pre0.z - v_r[2];  dd[3]  = pre0.w - v_r[3];
        dd[4]  = pre1.x - v_r[4];  dd[5]  = pre1.y - v_r[5];
        dd[6]  = pre1.z - v_r[6];  dd[7]  = pre1.w - v_r[7];
        dd[8]  = pre2.x - v_r[8];  dd[9]  = pre2.y - v_r[9];
        dd[10] = pre2.z - v_r[10]; dd[11] = pre2.w - v_r[11];
        if (v3) {
            dd[12] = pre3.x - v_r[12]; dd[13] = pre3.y - v_r[13];
            dd[14] = pre3.z - v_r[14]; dd[15] = pre3.w - v_r[15];
        } else {
            dd[12] = INFINITY; dd[13] = INFINITY;
            dd[14] = INFINITY; dd[15] = INFINITY;
        }
        // prefetch next queued row (latency hides under the reduce below)
        bool pf = false;
        if (qhead < qtail) { issue_row(cst4, unm[qhead], lane, pre0, pre1, pre2, pre3); pf = true; }
        // local depth-4 pairwise tree: (val, sec, slot, pcol); left wins ties
        float a1[NS], a2[NS]; int ai[NS], ap[NS];
        #pragma unroll
        for (int s = 0; s < NS; ++s) {
            a1[s] = dd[s]; a2[s] = INFINITY; ai[s] = s; ap[s] = pcol_r[s];
        }
        #pragma unroll
        for (int n = 8; n >= 1; n >>= 1) {
            #pragma unroll
            for (int i = 0; i < n; ++i) {
                bool tk = a1[2 * i + 1] < a1[2 * i];
                float m1 = tk ? a1[2 * i + 1] : a1[2 * i];
                float ms = tk ? fminf(a1[2 * i], a2[2 * i + 1])
                              : fminf(a1[2 * i + 1], a2[2 * i]);
                a1[i] = m1; a2[i] = ms;
                ai[i] = tk ? ai[2 * i + 1] : ai[2 * i];
                ap[i] = tk ? ap[2 * i + 1] : ap[2 * i];
            }
        }
        float lmin = a1[0];
        int ls = ai[0];
        int pv = ap[0];
        int myj = (lane << 2) + ((ls >> 2) << 8) + (ls & 3);
        float w1 = a1[0], w2 = a2[0];
        wave_fmin2_to63(w1, w2);
        float d1 = readlane63_f(w1);
        float d2 = readlane63_f(w2);
        unsigned long long eqm = __ballot(lmin == d1);
        int wl = __ffsll(eqm) - 1;
        int j1 = __builtin_amdgcn_readlane(myj, wl);
        int i0 = __builtin_amdgcn_readlane(pv, wl);
        bool take = (d1 < d2) || (i0 == 0);
        if (take) {
            if (i0 != 0) {
                // kicked row is the next pop when queue was empty: issue NOW
                if (!pf) issue_row(cst4, i0, lane, pre0, pre1, pre2, pre3);
                if (lane == 0) unm[qtail] = i0;
                qtail++;
            }
            int s1 = slot_of(j1), ow = owner_of(j1);
            float dv_ = d2 - d1;
            #pragma unroll
            for (int s = 0; s < NS; ++s)
                if (s == s1 && lane == ow) { v_r[s] -= dv_; pcol_r[s] = i_cur; }
            if (lane == 0) u_s[i_cur - 1] = d2;
        } else {
            if (lane == 0) { u_s[i_cur - 1] = d2; dij[dij_n] = i_cur; }
            dij_n++;
        }
    }
    // refresh register u mirrors after ARR writes
    u0 = u_s[lane];
    if (lane + 64 < TN) u1 = u_s[lane + 64];

    // --- shortest augmenting path for rows ARR couldn't place -------------
    if (dij_n > 0) issue_row(cst4, dij[0], lane, pre0, pre1, pre2, pre3);

    for (int ui = 0; ui < dij_n; ++ui) {
        int i_cur = dij[ui];
        unsigned used_mask = 0;
        float uic = readrow_u(u0, u1, i_cur - 1);
        #pragma unroll
        for (int s = 0; s < NS; ++s) way_r[s] = -1;
        dist_r[0]  = (pre0.x - uic) - v_r[0];
        dist_r[1]  = (pre0.y - uic) - v_r[1];
        dist_r[2]  = (pre0.z - uic) - v_r[2];
        dist_r[3]  = (pre0.w - uic) - v_r[3];
        dist_r[4]  = (pre1.x - uic) - v_r[4];
        dist_r[5]  = (pre1.y - uic) - v_r[5];
        dist_r[6]  = (pre1.z - uic) - v_r[6];
        dist_r[7]  = (pre1.w - uic) - v_r[7];
        dist_r[8]  = (pre2.x - uic) - v_r[8];
        dist_r[9]  = (pre2.y - uic) - v_r[9];
        dist_r[10] = (pre2.z - uic) - v_r[10];
        dist_r[11] = (pre2.w - uic) - v_r[11];
        if (v3) {
            dist_r[12] = (pre3.x - uic) - v_r[12];
            dist_r[13] = (pre3.y - uic) - v_r[13];
            dist_r[14] = (pre3.z - uic) - v_r[14];
            dist_r[15] = (pre3.w - uic) - v_r[15];
        } else {
            dist_r[12] = INFINITY; dist_r[13] = INFINITY;
            dist_r[14] = INFINITY; dist_r[15] = INFINITY;
        }
        if (ui + 1 < dij_n) issue_row(cst4, dij[ui + 1], lane, pre0, pre1, pre2, pre3);

        float dfin; int jfree;
        while (true) {
            // depth-4 pairwise min-tree with (slot, pcol) payload
            float dv[NS]; int dk[NS]; int pc[NS];
            #pragma unroll
            for (int s = 0; s < NS; ++s) {
                dv[s] = (used_mask & (1u << s)) ? INFINITY : dist_r[s];
                dk[s] = s;
                pc[s] = pcol_r[s];
            }
            #pragma unroll
            for (int n = 8; n >= 1; n >>= 1) {
                #pragma unroll
                for (int i = 0; i < n; ++i) {
                    bool tk = dv[2 * i + 1] < dv[2 * i];
                    dv[i] = tk ? dv[2 * i + 1] : dv[2 * i];
                    dk[i] = tk ? dk[2 * i + 1] : dk[2 * i];
                    pc[i] = tk ? pc[2 * i + 1] : pc[2 * i];
                }
            }
            float lv = dv[0];
            int s0 = dk[0];
            int li = (lane << 2) + ((s0 >> 2) << 8) + (s0 & 3);
            float dmin = readlane63_f(wave_fmin_to63(lv));
            unsigned long long eq = __ballot(lv == dmin);
            int winner = __ffsll(eq) - 1;
            int j1 = __builtin_amdgcn_readlane(li, winner);
            int pj1 = __builtin_amdgcn_readlane(pc[0], winner);
            if (pj1 == 0) { dfin = dmin; jfree = j1; break; }
            {
                int s1 = slot_of(j1), ow1 = owner_of(j1);
                if (lane == ow1) used_mask |= (1u << s1);
            }
            // row pj1 load issued first; readlane/bookkeeping overlap latency
            issue_row(cst4, pj1, lane, rc0, rc1, rc2, rc3);
            float ui0 = readrow_u(u0, u1, pj1 - 1);
            float off = dmin - ui0;   // wave-uniform
            #define RELAX(S, V) \
                if (!(used_mask & (1u << (S)))) { \
                    float nd = ((V) - v_r[S]) + off; \
                    if (nd < dist_r[S]) { dist_r[S] = nd; way_r[S] = j1; } }
            RELAX(0,  rc0.x) RELAX(1,  rc0.y) RELAX(2,  rc0.z) RELAX(3,  rc0.w)
            RELAX(4,  rc1.x) RELAX(5,  rc1.y) RELAX(6,  rc1.z) RELAX(7,  rc1.w)
            RELAX(8,  rc2.x) RELAX(9,  rc2.y) RELAX(10, rc2.z) RELAX(11, rc2.w)
            if (v3) {
                RELAX(12, rc3.x) RELAX(13, rc3.y) RELAX(14, rc3.z) RELAX(15, rc3.w)
            }
            #undef RELAX
        }
        // dual updates (once per path); pcol_r unchanged until augment below
        #pragma unroll
        for (int s = 0; s < NS; ++s) {
            if (used_mask & (1u << s)) {
                float a = dfin - dist_r[s];
                v_r[s] -= a;
                u_s[pcol_r[s] - 1] += a;   // distinct rows => distinct addresses
            }
        }
        if (lane == 0) u_s[i_cur - 1] += dfin;
        u0 = u_s[lane];
        if (lane + 64 < TN) u1 = u_s[lane + 64];
        // augment: walk way chain from the free column
        {
            int jj = jfree;
            while (true) {
                int wj = read_colreg16(way_r, jj);
                int pn = (wj < 0) ? i_cur : read_colreg16(pcol_r, wj);
                int sj = slot_of(jj), ow = owner_of(jj);
                #pragma unroll
                for (int s = 0; s < NS; ++s)
                    if (s == sj && lane == ow) pcol_r[s] = pn;
                if (wj < 0) break;
                jj = wj;
            }
        }
    }

    // --- emit: write pcol back to LDS by column for ascending-order pass --
    #pragma unroll
    for (int s = 0; s < NS; ++s) {
        int f = lane + ((s >> 2) << 6);
        int c = (f << 2) | (s & 3);
        if (f < F4N) p_s[c] = pcol_r[s];
    }
    float* rows = out + C_ELEMS + (size_t)b * TN;
    float* cols = out + C_ELEMS + (size_t)BS * TN + (size_t)b * TN;
    int base = 0;
    #pragma unroll
    for (int k = 0; k < NK; ++k) {
        int c = lane + (k << 6);
        int pv = (c < QN) ? p_s[c] : 0;
        unsigned long long mask = __ballot(pv > 0);
        if (pv > 0) {
            int rank = base + __popcll(mask & ((1ull << lane) - 1ull));
            rows[rank] = (float)c;
            cols[rank] = (float)(pv - 1);
        }
        base += __popcll(mask);
    }
}

extern "C" void kernel_launch(void* const* d_in, const int* in_sizes, int n_in,
                              void* d_out, int out_size, void* d_ws, size_t ws_size,
                              hipStream_t stream) {
    const float* logits = (const float*)d_in[0];        // (16,900,92)
    const float4* pboxes = (const float4*)d_in[1];      // (16,900,4) cxcywh
    const int* tids = (const int*)d_in[2];              // (1600,)
    const float4* tbox = (const float4*)d_in[3];        // (1600,4) xyxy
    float* out = (float*)d_out;

    float* cost_t = (float*)d_ws;                       // BS*TN*QN floats (5.76 MB)
    unsigned long long* rm =
        (unsigned long long*)(cost_t + (size_t)BS * TN * QN);  // NT u64 (8B-aligned)

    diag_cost_kernel<<<NQ / 4, 256, 0, stream>>>(logits, pboxes, (const int4*)tids, tbox, cost_t);
    rowmin_kernel<<<NT / 4, 256, 0, stream>>>(cost_t, rm);
    fused_cost_lsa_kernel<<<16 + NQ / 4, 256, 0, stream>>>(
        logits, pboxes, (const int4*)tids, tbox, cost_t, rm, out);
}